// Round 4
// baseline (1096.234 us; speedup 1.0000x reference)
//
#include <hip/hip_runtime.h>
#include <cstdint>
#include <cstddef>

#define H2 1024
#define TT 512
#define NSTEPS 64

using floatx4 = __attribute__((__ext_vector_type__(4))) float;
using half8   = __attribute__((__ext_vector_type__(8))) _Float16;
using half4   = __attribute__((__ext_vector_type__(4))) _Float16;

__device__ __forceinline__ float tanh_fast(float x) {
  return 1.0f - 2.0f / (__expf(2.0f * x) + 1.0f);
}

#define GLDS16(gp, lp)                                                         \
  __builtin_amdgcn_global_load_lds(                                            \
      (const __attribute__((address_space(1))) void*)(gp),                     \
      (__attribute__((address_space(3))) void*)(lp), 16, 0, 0)

#define SENTINEL 0xFFFFFFFFu  // -NaN bit pattern; never produced by the math

union ShMem {
  float t[64 * 69];            // phase-1 transpose tile (17.7 KB, stride 69)
  struct {
    _Float16 A[256 * 32];      // 16 KB  A tile: 256 e-rows x 32 k
    _Float16 B[128 * 32];      // 8 KB   B tile: 128 t-rows x 32 k
    float bias[H2];            // 4 KB
  } p2;
};

// ---------------------------------------------------------------------------
// Mega kernel. blocks 0..31: recurrence (sentinel-poll protocol, no barriers).
// blocks 32..287: t-major GEMM: in-block transpose h -> hhT slice, K-loop
// producing tanh(W h + b) as fp16, written in-place over own hhT slice.
// Deadlock-free for ANY dispatch order: gemm blocks have no cross-block deps.
// ---------------------------------------------------------------------------
__global__ __launch_bounds__(512, 2) void mega_kernel(
    const float* __restrict__ W, const float* __restrict__ bias,
    const float* __restrict__ u0, const float* __restrict__ h,
    const _Float16* __restrict__ Wh, _Float16* __restrict__ hhT,
    float* __restrict__ vbuf, float* __restrict__ norm2) {
  __shared__ ShMem sh;
  int tid = threadIdx.x;

  if (blockIdx.x < 32) {
    // ================= RECURRENCE ROLE =================
    int bid = blockIdx.x;
    int w = tid >> 6, lane = tid & 63;
    int r0 = bid * 32 + w * 4;  // wave owns rows r0..r0+3

    // W regs: lane holds W[r0+p][16*lane .. +16), p=0..3  (64 VGPRs)
    float4 wreg[4][4];
#pragma unroll
    for (int p = 0; p < 4; ++p) {
      const float4* wr = (const float4*)(W + ((size_t)(r0 + p) << 10) + 16 * lane);
#pragma unroll
      for (int j = 0; j < 4; ++j) wreg[p][j] = wr[j];
    }
    float bl = bias[r0 + (lane & 3)];

    for (int i = 0; i < NSTEPS; ++i) {
      float4 z[4];
      if (i == 0) {
        const float4* up = (const float4*)(u0 + 16 * lane);
#pragma unroll
        for (int j = 0; j < 4; ++j) z[j] = up[j];
      } else {
        const unsigned long long* src =
            (const unsigned long long*)(vbuf + (((size_t)(i - 1)) << 10) + 16 * lane);
        unsigned long long v[8];
        for (;;) {
          bool good = true;
#pragma unroll
          for (int j = 0; j < 8; ++j) {
            v[j] = __hip_atomic_load(src + j, __ATOMIC_RELAXED,
                                     __HIP_MEMORY_SCOPE_AGENT);
            if ((unsigned)(v[j]) == SENTINEL ||
                (unsigned)(v[j] >> 32) == SENTINEL)
              good = false;
          }
          if (__ballot(good) == ~0ull) break;
          __builtin_amdgcn_s_sleep(2);
        }
#pragma unroll
        for (int j = 0; j < 4; ++j) {
          union { unsigned long long u[2]; float4 f; } cv;
          cv.u[0] = v[2 * j];
          cv.u[1] = v[2 * j + 1];
          z[j] = cv.f;
        }
      }

      // norm^2 partial + 4 row-dot partials, butterfly over 64 lanes
      float sq = 0.f, d0 = 0.f, d1 = 0.f, d2 = 0.f, d3 = 0.f;
#pragma unroll
      for (int j = 0; j < 4; ++j) {
        float4 c = z[j];
        sq += c.x * c.x + c.y * c.y + c.z * c.z + c.w * c.w;
        float4 a;
        a = wreg[0][j]; d0 += a.x * c.x + a.y * c.y + a.z * c.z + a.w * c.w;
        a = wreg[1][j]; d1 += a.x * c.x + a.y * c.y + a.z * c.z + a.w * c.w;
        a = wreg[2][j]; d2 += a.x * c.x + a.y * c.y + a.z * c.z + a.w * c.w;
        a = wreg[3][j]; d3 += a.x * c.x + a.y * c.y + a.z * c.z + a.w * c.w;
      }
#pragma unroll
      for (int off = 1; off <= 32; off <<= 1) {
        sq += __shfl_xor(sq, off, 64);
        d0 += __shfl_xor(d0, off, 64);
        d1 += __shfl_xor(d1, off, 64);
        d2 += __shfl_xor(d2, off, 64);
        d3 += __shfl_xor(d3, off, 64);
      }
      float rs = (i == 0) ? 1.0f : 1.0f / fmaxf(sqrtf(sq), 1e-12f);
      if (bid == 0 && w == 0 && lane == 0 && i > 0) norm2[i - 1] = sq;

      if (lane < 4) {
        float d = (lane == 0) ? d0 : (lane == 1) ? d1 : (lane == 2) ? d2 : d3;
        float v = d * rs + bl;
        __hip_atomic_store(vbuf + (((size_t)i) << 10) + r0 + lane, v,
                           __ATOMIC_RELAXED, __HIP_MEMORY_SCOPE_AGENT);
      }
    }

    // block 0 / wave 0: compute and persist ||z_63||^2
    if (bid == 0 && w == 0) {
      const unsigned long long* src =
          (const unsigned long long*)(vbuf + (((size_t)(NSTEPS - 1)) << 10) + 16 * lane);
      unsigned long long v[8];
      for (;;) {
        bool good = true;
#pragma unroll
        for (int j = 0; j < 8; ++j) {
          v[j] = __hip_atomic_load(src + j, __ATOMIC_RELAXED,
                                   __HIP_MEMORY_SCOPE_AGENT);
          if ((unsigned)(v[j]) == SENTINEL || (unsigned)(v[j] >> 32) == SENTINEL)
            good = false;
        }
        if (__ballot(good) == ~0ull) break;
        __builtin_amdgcn_s_sleep(2);
      }
      float sq = 0.f;
#pragma unroll
      for (int j = 0; j < 8; ++j) {
        union { unsigned long long u; float f[2]; } cv;
        cv.u = v[j];
        sq += cv.f[0] * cv.f[0] + cv.f[1] * cv.f[1];
      }
#pragma unroll
      for (int off = 1; off <= 32; off <<= 1) sq += __shfl_xor(sq, off, 64);
      if (lane == 0) norm2[NSTEPS - 1] = sq;
    }
    return;
  }

  // ================= GEMM ROLE =================
  int gb = blockIdx.x - 32;  // 0..255
  int n = gb >> 2;
  int t0 = (gb & 3) * 128;
  int w = tid >> 6, lane = tid & 63;
  int q = lane >> 4, m = lane & 15;
  int we = w >> 1, wt = w & 1;  // wave grid: 4 (e) x 2 (t), wave tile 64e x 64t

  // ---- Phase 1: transpose own h slice -> hhT[n][t0..t0+128][d] fp16
  _Float16* hT = hhT + (((size_t)n) << 19);
  {
    const float* hb = h + (((size_t)n) << 19);
    for (int c = 0; c < 16; ++c) {        // d-chunks of 64
      for (int th = 0; th < 2; ++th) {    // t-halves of 64
#pragma unroll
        for (int p = 0; p < 2; ++p) {
          int slot = tid + 512 * p;       // 1024 float4 slots
          int dr = slot >> 4, tc2 = (slot & 15) << 2;
          float4 v = *(const float4*)(hb + (size_t)(64 * c + dr) * TT + t0 +
                                      64 * th + tc2);
          sh.t[dr * 69 + tc2 + 0] = v.x;
          sh.t[dr * 69 + tc2 + 1] = v.y;
          sh.t[dr * 69 + tc2 + 2] = v.z;
          sh.t[dr * 69 + tc2 + 3] = v.w;
        }
        __syncthreads();
        int tr = tid >> 3, sg = tid & 7;
        half8 hv;
#pragma unroll
        for (int u = 0; u < 8; ++u)
          hv[u] = (_Float16)sh.t[(8 * sg + u) * 69 + tr];
        *(half8*)(hT + (size_t)(t0 + 64 * th + tr) * H2 + 64 * c + 8 * sg) = hv;
        __syncthreads();
      }
    }
  }

  // ---- Phase 2: K-loop. C[e,t] = sum_d Wh[e,d] * hhT[n,t,d]
  sh.p2.bias[tid] = bias[tid];
  sh.p2.bias[tid + 512] = bias[tid + 512];
  __syncthreads();

  int rl = lane >> 2, kseg = (lane & 3) * 8;  // staging: row-in-16, 16B seg
  char* lA0 = (char*)sh.p2.A + (32 * w) * 64;
  char* lA1 = lA0 + 1024;
  char* lB0 = (char*)sh.p2.B + (16 * w) * 64;

  half4 uh[4][4][4];  // tanh'd fp16 results: [e-iter][i][j], 4 halfs each

#pragma unroll
  for (int it = 0; it < 4; ++it) {
    int e0 = it * 256;
    floatx4 acc[4][4];
#pragma unroll
    for (int i = 0; i < 4; ++i)
#pragma unroll
      for (int j = 0; j < 4; ++j) acc[i][j] = {0.f, 0.f, 0.f, 0.f};

    const _Float16* gA = Wh + (((size_t)(e0 + 32 * w + rl)) << 10) + kseg;
    const _Float16* gB = hT + (((size_t)(t0 + 16 * w + rl)) << 10) + kseg;

#pragma unroll 1
    for (int k0 = 0; k0 < H2; k0 += 32) {
      GLDS16(gA + k0, lA0);
      GLDS16(gA + k0 + (16 << 10), lA1);
      GLDS16(gB + k0, lB0);
      __syncthreads();

      half8 af[4], bf[4];
#pragma unroll
      for (int i = 0; i < 4; ++i)
        af[i] = *(const half8*)&sh.p2.A[(we * 64 + i * 16 + m) * 32 + q * 8];
#pragma unroll
      for (int j = 0; j < 4; ++j)
        bf[j] = *(const half8*)&sh.p2.B[(wt * 64 + j * 16 + m) * 32 + q * 8];
#pragma unroll
      for (int i = 0; i < 4; ++i)
#pragma unroll
        for (int j = 0; j < 4; ++j)
          acc[i][j] = __builtin_amdgcn_mfma_f32_16x16x32_f16(af[i], bf[j],
                                                             acc[i][j], 0, 0, 0);
      __syncthreads();
    }

    // epilogue: +bias, tanh, pack fp16 into regs (written to global at end)
#pragma unroll
    for (int i = 0; i < 4; ++i) {
#pragma unroll
      for (int j = 0; j < 4; ++j) {
        half4 hv;
#pragma unroll
        for (int reg = 0; reg < 4; ++reg) {
          float bb = sh.p2.bias[e0 + we * 64 + i * 16 + q * 4 + reg];
          hv[reg] = (_Float16)tanh_fast(acc[i][j][reg] + bb);
        }
        uh[it][i][j] = hv;
      }
    }
  }

  // ---- final: overwrite own hhT slice in-place with u_it[n][t][e]
#pragma unroll
  for (int it = 0; it < 4; ++it)
#pragma unroll
    for (int i = 0; i < 4; ++i)
#pragma unroll
      for (int j = 0; j < 4; ++j) {
        int tg = t0 + wt * 64 + j * 16 + m;
        int eg = it * 256 + we * 64 + i * 16 + q * 4;
        *(half4*)(hT + (size_t)tg * H2 + eg) = uh[it][i][j];
      }
}

// ---------------------------------------------------------------------------
// Pre-pass: W fp32 -> fp16
// ---------------------------------------------------------------------------
__global__ __launch_bounds__(256) void wconv_kernel(const float* __restrict__ W,
                                                    _Float16* __restrict__ Wh) {
  int i = blockIdx.x * 256 + threadIdx.x;
  float4 v = ((const float4*)W)[i];
  half4 o = {(_Float16)v.x, (_Float16)v.y, (_Float16)v.z, (_Float16)v.w};
  ((half4*)Wh)[i] = o;
}

// ---------------------------------------------------------------------------
// scores[n,t] = sum_e u_it[n][t][e] * u_ws[n][e];  grid (4 t-chunks, 64 n)
// ---------------------------------------------------------------------------
__global__ __launch_bounds__(256) void scores_kernel(
    const _Float16* __restrict__ uit, const float* __restrict__ vbuf,
    const float* __restrict__ norm2, float* __restrict__ scores) {
  __shared__ float uws[1040];  // swizzled: addr = i + (i>>6)
  int n = blockIdx.y, t0 = blockIdx.x * 128;
  int tid = threadIdx.x;

  float rs = 1.0f / fmaxf(sqrtf(norm2[n]), 1e-12f);
  float4 zv = ((const float4*)(vbuf + ((size_t)n << 10)))[tid];
  float4 sv = {zv.x * rs, zv.y * rs, zv.z * rs, zv.w * rs};
  *(float4*)(uws + 4 * tid + (tid >> 4)) = sv;
  __syncthreads();

  int g = tid & 15, rr = tid >> 4;
  const float* ub = uws + 65 * g;
#pragma unroll 1
  for (int pass = 0; pass < 8; ++pass) {
    int t = t0 + pass * 16 + rr;
    const half8* up = (const half8*)(uit + ((size_t)n << 19) +
                                     ((size_t)t << 10) + g * 64);
    float s = 0.f;
#pragma unroll
    for (int j = 0; j < 8; ++j) {
      half8 hv = up[j];
#pragma unroll
      for (int u = 0; u < 8; ++u) s += (float)hv[u] * ub[8 * j + u];
    }
    s += __shfl_xor(s, 1, 64);
    s += __shfl_xor(s, 2, 64);
    s += __shfl_xor(s, 4, 64);
    s += __shfl_xor(s, 8, 64);
    if (g == 0) scores[(size_t)n * TT + t] = s;
  }
}

// ---------------------------------------------------------------------------
// Fused softmax + weighted sum (unchanged, verified)
// ---------------------------------------------------------------------------
__global__ __launch_bounds__(256) void out_kernel(
    const float* __restrict__ h, const float* __restrict__ scores,
    float* __restrict__ out) {
  int n = blockIdx.y;
  int ds = blockIdx.x;
  int tid = threadIdx.x;
  int w = tid >> 6, lane = tid & 63;

  __shared__ float sa[TT];
  __shared__ float wred[8];

  float s0 = scores[(size_t)n * TT + tid];
  float s1 = scores[(size_t)n * TT + 256 + tid];

  float mx = fmaxf(s0, s1);
#pragma unroll
  for (int off = 32; off >= 1; off >>= 1) mx = fmaxf(mx, __shfl_xor(mx, off, 64));
  if (lane == 0) wred[w] = mx;
  __syncthreads();
  mx = fmaxf(fmaxf(wred[0], wred[1]), fmaxf(wred[2], wred[3]));

  float e0 = __expf(s0 - mx);
  float e1 = __expf(s1 - mx);
  float ssum = e0 + e1;
#pragma unroll
  for (int off = 32; off >= 1; off >>= 1) ssum += __shfl_xor(ssum, off, 64);
  if (lane == 0) wred[4 + w] = ssum;
  __syncthreads();
  ssum = wred[4] + wred[5] + wred[6] + wred[7];
  float inv = 1.0f / ssum;
  sa[tid] = e0 * inv;
  sa[tid + 256] = e1 * inv;
  __syncthreads();

  int d0 = ds * 64 + w * 16;
  const float4* hb = reinterpret_cast<const float4*>(h + (size_t)n * H2 * TT);
#pragma unroll 1
  for (int rr = 0; rr < 16; ++rr) {
    int d = d0 + rr;
    const float4* hr = hb + (size_t)d * (TT / 4);
    float4 a4 = hr[lane];
    float4 b4 = hr[64 + lane];
    int t0 = 4 * lane;
    float acc = a4.x * sa[t0] + a4.y * sa[t0 + 1] + a4.z * sa[t0 + 2] +
                a4.w * sa[t0 + 3] + b4.x * sa[256 + t0] +
                b4.y * sa[256 + t0 + 1] + b4.z * sa[256 + t0 + 2] +
                b4.w * sa[256 + t0 + 3];
#pragma unroll
    for (int off = 1; off <= 32; off <<= 1) acc += __shfl_xor(acc, off, 64);
    if (lane == 0) out[(size_t)n * H2 + d] = acc;
  }
}

// ---------------------------------------------------------------------------
extern "C" void kernel_launch(void* const* d_in, const int* in_sizes, int n_in,
                              void* d_out, int out_size, void* d_ws, size_t ws_size,
                              hipStream_t stream) {
  const float* h    = (const float*)d_in[0];  // (64, 1024, 512)
  const float* W    = (const float*)d_in[1];  // (1024, 1024)
  const float* bias = (const float*)d_in[2];  // (1024,)
  const float* u0   = (const float*)d_in[3];  // (1024,)
  float* out = (float*)d_out;                 // (64, 1024)

  float* wsf    = (float*)d_ws;
  float* norm2  = wsf;                         // 64
  float* scores = wsf + 64;                    // 64*512
  float* vbuf   = wsf + 64 + (size_t)NSTEPS * TT;        // 64*1024
  _Float16* Wh  = (_Float16*)(vbuf + (size_t)NSTEPS * H2);   // 1M halfs
  _Float16* hhT = Wh + (size_t)H2 * H2;        // 64 MB: hhT then u_it in-place

  // sentinel-init vbuf (the recurrence's poll target)
  hipMemsetAsync(vbuf, 0xFF, (size_t)NSTEPS * H2 * sizeof(float), stream);

  wconv_kernel<<<dim3(H2 * H2 / 1024), dim3(256), 0, stream>>>(W, Wh);

  mega_kernel<<<dim3(32 + 256), dim3(512), 0, stream>>>(W, bias, u0, h, Wh,
                                                        hhT, vbuf, norm2);

  scores_kernel<<<dim3(4, 64), dim3(256), 0, stream>>>(hhT, vbuf, norm2,
                                                       scores);

  out_kernel<<<dim3(16, 64), dim3(256), 0, stream>>>(h, scores, out);

  (void)in_sizes; (void)n_in; (void)out_size; (void)ws_size;
}